// Round 11
// baseline (1657.323 us; speedup 1.0000x reference)
//
#include <hip/hip_runtime.h>
#include <hip/hip_bf16.h>

// DirectionalPropagation1D v11: B=16, C=64, H=256, W=256, N=4096 seqs.
// W-SEGMENTED single-wave blocks: grid = 256 seq-tiles x 4 segments of 64 w.
// Segments 1-3 run a 24-step warmup from zero state (recurrence gain/step
// ~0.2 -> warmup error ~1e-8, far below bf16 ulp; deterministic).
// Each block = ONE wave, fully self-sufficient, zero barriers:
//   - state in registers via permuted-Ws (v5/v9-validated),
//   - F operands: 16 scalar f32 gathers/step (64B feat lines serve 16 w via
//     L2 -> HBM bytes ~ feat x1.29), packed to bf16 in-wave, 2-step pipeline,
//   - out staged in v5-validated og LDS (32 KB), drained as full 64B lines
//     every 16 steps (v10 showed direct 16B stores -> 3.2x write explosion).

typedef __attribute__((ext_vector_type(8))) short short8;
typedef __attribute__((ext_vector_type(4))) short short4v;
typedef __attribute__((ext_vector_type(2))) short short2v;
typedef __attribute__((ext_vector_type(4))) float f32x4;

union FragU { unsigned int u[4]; short8 v; };
union PkU { unsigned int u; short2v s2; };

__device__ __forceinline__ unsigned int pk2(float a, float b) {
    unsigned short lo = __bfloat16_as_ushort(__float2bfloat16(a));
    unsigned short hi = __bfloat16_as_ushort(__float2bfloat16(b));
    return (unsigned int)lo | ((unsigned int)hi << 16);
}
__device__ __forceinline__ float b2f(short x) {
    return __uint_as_float(((unsigned int)(unsigned short)x) << 16);
}

// out staging [o64][n16][w16] bf16 (same pure function both sides; writer
// uses the validated lane-constant decomposition, reader calls ogi()).
__device__ __forceinline__ int ogi(int o, int n, int w) {
    return (o * 256 + n * 16 + w) ^ ((((o >> 2) ^ (n >> 2)) & 3) << 2);
}

__global__ __launch_bounds__(64) void dp_v11_kernel(
    const float* __restrict__ feat, const float* __restrict__ conf,
    const float* __restrict__ Wi, const float* __restrict__ bi,
    const float* __restrict__ Ws, const float* __restrict__ bs,
    const float* __restrict__ bias, float* __restrict__ outp)
{
    __shared__ unsigned short og[16384];     // 32 KB out bf16 tile

    const int lane = threadIdx.x & 63;
    const int l15 = lane & 15, g4 = lane >> 4;
    const int bid = blockIdx.x;
    const int seg = bid & 3;                 // w-segment
    const int nb = bid >> 2;                 // seq tile 0..255
    const int b = nb >> 4, h0 = (nb & 15) * 16;

    const int w0 = seg * 64;                 // first output step
    const int wS = (seg == 0) ? 0 : (w0 - 24);  // warmup start (even)
    const int wE = w0 + 64;

    // ---- weights (v9 verbatim): Ai natural, As permuted K(h,g4,j) ----
    FragU Ai[4][2], As[4][2];
    #pragma unroll
    for (int t = 0; t < 4; ++t)
        #pragma unroll
        for (int h = 0; h < 2; ++h) {
            const float* si = Wi + (16 * t + l15) * 64 + 32 * h + g4 * 8;
            const float* ss = Ws + (16 * t + l15) * 64;
            #pragma unroll
            for (int d = 0; d < 4; ++d) {
                Ai[t][h].u[d] = pk2(si[2 * d], si[2 * d + 1]);
                const int c0 = 16 * (2 * h + (d >> 1)) + 4 * g4 + 2 * (d & 1);
                As[t][h].u[d] = pk2(ss[c0], ss[c0 + 1]);
            }
        }
    f32x4 binit[4];
    #pragma unroll
    for (int t = 0; t < 4; ++t)
        #pragma unroll
        for (int r = 0; r < 4; ++r) {
            int o = 16 * t + 4 * g4 + r;
            binit[t][r] = bi[o] + bs[o] + bias[o];
        }

    FragU S0, S1;
    #pragma unroll
    for (int d = 0; d < 4; ++d) { S0.u[d] = 0u; S1.u[d] = 0u; }

    // per-lane bases
    const float* fl = feat + (size_t)b * 64 * 65536 + (size_t)(h0 + l15) * 256;
    const float* gb = conf + ((size_t)(b * 256) + h0 + l15) * 256;
    const int swz = ((g4 ^ (l15 >> 2)) & 3) << 2;
    const int ogl = g4 * 1024 + l15 * 16;
    const int dn = lane >> 2, dwq = lane & 3;      // drain lane roles
    float* const ob = outp + ((size_t)(b * 64) * 256 + h0 + dn) * 256 + 4 * dwq;

    auto mstep = [&](const short8& F0, const short8& F1, float (&cur)[4][4]) {
        f32x4 a0 = binit[0], a1 = binit[1], a2 = binit[2], a3 = binit[3];
        a0 = __builtin_amdgcn_mfma_f32_16x16x32_bf16(Ai[0][0].v, F0, a0, 0, 0, 0);
        a1 = __builtin_amdgcn_mfma_f32_16x16x32_bf16(Ai[1][0].v, F0, a1, 0, 0, 0);
        a2 = __builtin_amdgcn_mfma_f32_16x16x32_bf16(Ai[2][0].v, F0, a2, 0, 0, 0);
        a3 = __builtin_amdgcn_mfma_f32_16x16x32_bf16(Ai[3][0].v, F0, a3, 0, 0, 0);
        a0 = __builtin_amdgcn_mfma_f32_16x16x32_bf16(Ai[0][1].v, F1, a0, 0, 0, 0);
        a1 = __builtin_amdgcn_mfma_f32_16x16x32_bf16(Ai[1][1].v, F1, a1, 0, 0, 0);
        a2 = __builtin_amdgcn_mfma_f32_16x16x32_bf16(Ai[2][1].v, F1, a2, 0, 0, 0);
        a3 = __builtin_amdgcn_mfma_f32_16x16x32_bf16(Ai[3][1].v, F1, a3, 0, 0, 0);
        a0 = __builtin_amdgcn_mfma_f32_16x16x32_bf16(As[0][0].v, S0.v, a0, 0, 0, 0);
        a1 = __builtin_amdgcn_mfma_f32_16x16x32_bf16(As[1][0].v, S0.v, a1, 0, 0, 0);
        a2 = __builtin_amdgcn_mfma_f32_16x16x32_bf16(As[2][0].v, S0.v, a2, 0, 0, 0);
        a3 = __builtin_amdgcn_mfma_f32_16x16x32_bf16(As[3][0].v, S0.v, a3, 0, 0, 0);
        a0 = __builtin_amdgcn_mfma_f32_16x16x32_bf16(As[0][1].v, S1.v, a0, 0, 0, 0);
        a1 = __builtin_amdgcn_mfma_f32_16x16x32_bf16(As[1][1].v, S1.v, a1, 0, 0, 0);
        a2 = __builtin_amdgcn_mfma_f32_16x16x32_bf16(As[2][1].v, S1.v, a2, 0, 0, 0);
        a3 = __builtin_amdgcn_mfma_f32_16x16x32_bf16(As[3][1].v, S1.v, a3, 0, 0, 0);
        #pragma unroll
        for (int r = 0; r < 4; ++r) {
            cur[0][r] = fmaxf(a0[r], 0.f);
            cur[1][r] = fmaxf(a1[r], 0.f);
            cur[2][r] = fmaxf(a2[r], 0.f);
            cur[3][r] = fmaxf(a3[r], 0.f);
        }
    };
    auto rebuild = [&](const float (&cur)[4][4], float gv) {
        float g0[4], g1[4], g2[4], g3[4];
        #pragma unroll
        for (int r = 0; r < 4; ++r) {
            g0[r] = cur[0][r] * gv; g1[r] = cur[1][r] * gv;
            g2[r] = cur[2][r] * gv; g3[r] = cur[3][r] * gv;
        }
        S0.u[0] = pk2(g0[0], g0[1]); S0.u[1] = pk2(g0[2], g0[3]);
        S0.u[2] = pk2(g1[0], g1[1]); S0.u[3] = pk2(g1[2], g1[3]);
        S1.u[0] = pk2(g2[0], g2[1]); S1.u[1] = pk2(g2[2], g2[3]);
        S1.u[2] = pk2(g3[0], g3[1]); S1.u[3] = pk2(g3[2], g3[3]);
    };

    auto ldfr = [&](float (&fr)[16], int w) {   // 16 scalar gathers, L2-line reuse
        #pragma unroll
        for (int j = 0; j < 8; ++j) {
            fr[j]     = fl[(size_t)(8 * g4 + j) * 65536 + w];
            fr[8 + j] = fl[(size_t)(32 + 8 * g4 + j) * 65536 + w];
        }
    };
    auto pack = [&](const float (&fr)[16], short8& F0, short8& F1) {
        FragU f0, f1;
        #pragma unroll
        for (int d = 0; d < 4; ++d) {
            f0.u[d] = pk2(fr[2 * d], fr[2 * d + 1]);
            f1.u[d] = pk2(fr[8 + 2 * d], fr[8 + 2 * d + 1]);
        }
        F0 = f0.v; F1 = f1.v;
    };

    float curE[4][4];

    auto do_step = [&](int w, float (&fr)[16], float& gsl) {
        short8 F0, F1;
        pack(fr, F0, F1);                 // waits on loads issued 2 steps ago
        const float gcur = gsl;           // g[w+1]
        if (w + 2 < wE) {                 // refill: raw(w+2), g[w+3]
            ldfr(fr, w + 2);
            int gi = w + 3; if (gi > 255) gi = 255;
            gsl = gb[gi];
        }
        float cur[4][4];
        mstep(F0, F1, cur);
        if (w >= w0) {                    // out staging (skip in warmup)
            const int u = w & 15;
            if ((u & 1) == 0) {
                #pragma unroll
                for (int t = 0; t < 4; ++t)
                    #pragma unroll
                    for (int r = 0; r < 4; ++r) curE[t][r] = cur[t][r];
            } else {
                unsigned short* opb = og + ogl + ((u - 1) ^ swz);
                #pragma unroll
                for (int t = 0; t < 4; ++t)
                    #pragma unroll
                    for (int r = 0; r < 4; ++r) {
                        PkU pk; pk.u = pk2(curE[t][r], cur[t][r]);
                        *(short2v*)&opb[t * 4096 + r * 256] = pk.s2;
                    }
            }
        }
        rebuild(cur, gcur);               // final-step rebuild harmless (unused)
        if (w >= w0 && (w & 15) == 15) {  // drain full 64B lines; same-wave DS order
            const int wt = w - 15;
            #pragma unroll 8
            for (int o = 0; o < 64; ++o) {
                short4v d = *(const short4v*)&og[ogi(o, dn, 4 * dwq)];
                f32x4 o4 = { b2f(d.x), b2f(d.y), b2f(d.z), b2f(d.w) };
                *(f32x4*)(ob + (size_t)o * 65536 + wt) = o4;
            }
        }
    };

    // ---- prologue: prime the 2-step pipeline ----
    float frA[16], frB[16];
    float gEv, gOd;
    ldfr(frA, wS);
    ldfr(frB, wS + 1);
    gEv = gb[wS + 1];
    { int gi = wS + 2; if (gi > 255) gi = 255; gOd = gb[gi]; }

    #pragma unroll 1
    for (int wp = wS; wp < wE; wp += 2) {
        do_step(wp, frA, gEv);
        do_step(wp + 1, frB, gOd);
    }
}

extern "C" void kernel_launch(void* const* d_in, const int* in_sizes, int n_in,
                              void* d_out, int out_size, void* d_ws, size_t ws_size,
                              hipStream_t stream) {
    const float* feat = (const float*)d_in[0];
    const float* conf = (const float*)d_in[1];
    const float* Wi   = (const float*)d_in[2];
    const float* bi   = (const float*)d_in[3];
    const float* Ws   = (const float*)d_in[4];
    const float* bs   = (const float*)d_in[5];
    const float* bias = (const float*)d_in[6];
    float* out = (float*)d_out;
    (void)d_ws; (void)ws_size; (void)in_sizes; (void)n_in; (void)out_size;

    dp_v11_kernel<<<1024, 64, 0, stream>>>(feat, conf, Wi, bi, Ws, bs, bias, out);
}

// Round 12
// 258.903 us; speedup vs baseline: 6.4013x; 6.4013x over previous
//
#include <hip/hip_runtime.h>
#include <hip/hip_bf16.h>

// DirectionalPropagation1D v12: B=16, C=64, H=256, W=256, N=4096 seqs.
// 256 blocks = 128 seq-tiles(32 seqs) x 2 w-segments(128 w, +24-step warmup
// for seg 1 -- warmup exactness validated empirically in R11: absmax same).
// 4 waves: wid0/1 = recurrence for n=[0,16)/[16,32) (v9 code verbatim,
// register state via permuted-Ws, each on its own SIMD); wid2 = feat stager
// (8-w chunks, ping-pong LDS, 4-deep load pipeline); wid3 = out drainer
// (single 16-w og buffer, full-64B-line stores once per chunk-pair, fenced
// by one barB per pair). Rec waves self-load gates (v5 pattern).
// LDS 128 KB. All barriers lgkm-only.

typedef __attribute__((ext_vector_type(8))) short short8;
typedef __attribute__((ext_vector_type(4))) short short4v;
typedef __attribute__((ext_vector_type(2))) short short2v;
typedef __attribute__((ext_vector_type(4))) float f32x4;

union FragU { unsigned int u[4]; short8 v; };
union PkU { unsigned int u; short2v s2; };

__device__ __forceinline__ unsigned int pk2(float a, float b) {
    unsigned short lo = __bfloat16_as_ushort(__float2bfloat16(a));
    unsigned short hi = __bfloat16_as_ushort(__float2bfloat16(b));
    return (unsigned int)lo | ((unsigned int)hi << 16);
}
__device__ __forceinline__ float b2f(short x) {
    return __uint_as_float(((unsigned int)(unsigned short)x) << 16);
}

// fs: [w8][n32][c64] bf16 per buffer: idx = w*2048 + ((n*64+c) ^ ((n&7)<<3))
// og16: [o64][n32][w16] bf16: idx = (o*512 + n*16 + w) ^ (((o>>2)&3)<<2)
//   (XOR touches only w-bits 2-3 -> per-(o,n) bijection on the 16 w-slots;
//    chunk halves map to disjoint slot sets, drain inverts identically.)

#define BAR() asm volatile("s_waitcnt lgkmcnt(0)\n\ts_barrier" ::: "memory")

__global__ __launch_bounds__(256, 1) void dp_v12_kernel(
    const float* __restrict__ feat, const float* __restrict__ conf,
    const float* __restrict__ Wi, const float* __restrict__ bi,
    const float* __restrict__ Ws, const float* __restrict__ bs,
    const float* __restrict__ bias, float* __restrict__ outp)
{
    __shared__ unsigned short fs[2][16384];   // 64 KB feat bf16 ping-pong
    __shared__ unsigned short og16[32768];    // 64 KB out bf16, 16-w pairs

    const int tid = threadIdx.x, lane = tid & 63, wid = tid >> 6;
    const int l15 = lane & 15, g4 = lane >> 4;
    const int bid = blockIdx.x;
    const int seg = bid & 1, nb = bid >> 1;
    const int b = nb >> 3, h0 = (nb & 7) * 32;
    const int j0 = seg << 4;                  // first output chunk (0 / 16)
    const int kS = seg ? 13 : 0;              // first chunk (incl. 24-w warmup)
    const int kE = j0 + 16;

    const float* fb = feat + (size_t)b * 64 * 65536 + (size_t)h0 * 256;

    if (wid <= 1) {
        // ============ recurrence wave: rows n = 16*wid + l15 ============
        const int nn = 16 * wid + l15;

        FragU Ai[4][2], As[4][2];
        #pragma unroll
        for (int t = 0; t < 4; ++t)
            #pragma unroll
            for (int h = 0; h < 2; ++h) {
                const float* si = Wi + (16 * t + l15) * 64 + 32 * h + g4 * 8;
                const float* ss = Ws + (16 * t + l15) * 64;
                #pragma unroll
                for (int d = 0; d < 4; ++d) {
                    Ai[t][h].u[d] = pk2(si[2 * d], si[2 * d + 1]);
                    const int c0 = 16 * (2 * h + (d >> 1)) + 4 * g4 + 2 * (d & 1);
                    As[t][h].u[d] = pk2(ss[c0], ss[c0 + 1]);
                }
            }
        f32x4 binit[4];
        #pragma unroll
        for (int t = 0; t < 4; ++t)
            #pragma unroll
            for (int r = 0; r < 4; ++r) {
                int o = 16 * t + 4 * g4 + r;
                binit[t][r] = bi[o] + bs[o] + bias[o];
            }

        FragU S0, S1;
        #pragma unroll
        for (int d = 0; d < 4; ++d) { S0.u[d] = 0u; S1.u[d] = 0u; }

        const float* gp = conf + ((size_t)(b * 256) + h0 + nn) * 256;
        f32x4 gc0 = *(const f32x4*)(gp + 8 * kS);
        f32x4 gc1 = *(const f32x4*)(gp + 8 * kS + 4);
        f32x4 gn0 = *(const f32x4*)(gp + 8 * kS + 8);
        f32x4 gn1 = *(const f32x4*)(gp + 8 * kS + 12);

        const int foA = (nn * 64 + 8 * g4) ^ ((l15 & 7) << 3);
        const int foB = (nn * 64 + 32 + 8 * g4) ^ ((l15 & 7) << 3);
        const int obL = 4 * g4 * 512 + nn * 16;   // + t*8192 + r*512 + w-slot
        const int swzv = g4 << 2;

        float curE[4][4];

        auto mstep = [&](const short8& F0, const short8& F1, float (&cur)[4][4]) {
            f32x4 a0 = binit[0], a1 = binit[1], a2 = binit[2], a3 = binit[3];
            a0 = __builtin_amdgcn_mfma_f32_16x16x32_bf16(Ai[0][0].v, F0, a0, 0, 0, 0);
            a1 = __builtin_amdgcn_mfma_f32_16x16x32_bf16(Ai[1][0].v, F0, a1, 0, 0, 0);
            a2 = __builtin_amdgcn_mfma_f32_16x16x32_bf16(Ai[2][0].v, F0, a2, 0, 0, 0);
            a3 = __builtin_amdgcn_mfma_f32_16x16x32_bf16(Ai[3][0].v, F0, a3, 0, 0, 0);
            a0 = __builtin_amdgcn_mfma_f32_16x16x32_bf16(Ai[0][1].v, F1, a0, 0, 0, 0);
            a1 = __builtin_amdgcn_mfma_f32_16x16x32_bf16(Ai[1][1].v, F1, a1, 0, 0, 0);
            a2 = __builtin_amdgcn_mfma_f32_16x16x32_bf16(Ai[2][1].v, F1, a2, 0, 0, 0);
            a3 = __builtin_amdgcn_mfma_f32_16x16x32_bf16(Ai[3][1].v, F1, a3, 0, 0, 0);
            a0 = __builtin_amdgcn_mfma_f32_16x16x32_bf16(As[0][0].v, S0.v, a0, 0, 0, 0);
            a1 = __builtin_amdgcn_mfma_f32_16x16x32_bf16(As[1][0].v, S0.v, a1, 0, 0, 0);
            a2 = __builtin_amdgcn_mfma_f32_16x16x32_bf16(As[2][0].v, S0.v, a2, 0, 0, 0);
            a3 = __builtin_amdgcn_mfma_f32_16x16x32_bf16(As[3][0].v, S0.v, a3, 0, 0, 0);
            a0 = __builtin_amdgcn_mfma_f32_16x16x32_bf16(As[0][1].v, S1.v, a0, 0, 0, 0);
            a1 = __builtin_amdgcn_mfma_f32_16x16x32_bf16(As[1][1].v, S1.v, a1, 0, 0, 0);
            a2 = __builtin_amdgcn_mfma_f32_16x16x32_bf16(As[2][1].v, S1.v, a2, 0, 0, 0);
            a3 = __builtin_amdgcn_mfma_f32_16x16x32_bf16(As[3][1].v, S1.v, a3, 0, 0, 0);
            #pragma unroll
            for (int r = 0; r < 4; ++r) {
                cur[0][r] = fmaxf(a0[r], 0.f);
                cur[1][r] = fmaxf(a1[r], 0.f);
                cur[2][r] = fmaxf(a2[r], 0.f);
                cur[3][r] = fmaxf(a3[r], 0.f);
            }
        };
        auto rebuild = [&](const float (&cur)[4][4], float gv) {
            float q0[4], q1[4], q2[4], q3[4];
            #pragma unroll
            for (int r = 0; r < 4; ++r) {
                q0[r] = cur[0][r] * gv; q1[r] = cur[1][r] * gv;
                q2[r] = cur[2][r] * gv; q3[r] = cur[3][r] * gv;
            }
            S0.u[0] = pk2(q0[0], q0[1]); S0.u[1] = pk2(q0[2], q0[3]);
            S0.u[2] = pk2(q1[0], q1[1]); S0.u[3] = pk2(q1[2], q1[3]);
            S1.u[0] = pk2(q2[0], q2[1]); S1.u[1] = pk2(q2[2], q2[3]);
            S1.u[2] = pk2(q3[0], q3[1]); S1.u[3] = pk2(q3[2], q3[3]);
        };

        BAR();  // prologue: chunk kS staged
        #pragma unroll 1
        for (int j = kS; j < kE; ++j) {
            if (((j & 1) == 0) && (j >= j0 + 2)) BAR();   // barB: drain snapshot
            const unsigned short* fsb = fs[j & 1];
            const int whalf = (j & 1) << 3;
            const bool ow = (j >= j0);
            #pragma unroll
            for (int u = 0; u < 8; ++u) {
                short8 F0 = *(const short8*)&fsb[u * 2048 + foA];
                short8 F1 = *(const short8*)&fsb[u * 2048 + foB];
                float cur[4][4];
                mstep(F0, F1, cur);
                if (ow) {
                    if ((u & 1) == 0) {
                        #pragma unroll
                        for (int t = 0; t < 4; ++t)
                            #pragma unroll
                            for (int r = 0; r < 4; ++r) curE[t][r] = cur[t][r];
                    } else {
                        const int wim = ((whalf + u - 1) ^ swzv) + obL;
                        #pragma unroll
                        for (int t = 0; t < 4; ++t)
                            #pragma unroll
                            for (int r = 0; r < 4; ++r) {
                                PkU pk; pk.u = pk2(curE[t][r], cur[t][r]);
                                *(short2v*)&og16[t * 8192 + r * 512 + wim] = pk.s2;
                            }
                    }
                }
                float gv;
                if (u < 3) gv = gc0[u + 1];
                else if (u < 7) gv = gc1[u - 3];
                else gv = gn0[0];
                rebuild(cur, gv);
            }
            gc0 = gn0; gc1 = gn1;
            if (j < 30) {
                gn0 = *(const f32x4*)(gp + 8 * j + 16);
                gn1 = *(const f32x4*)(gp + 8 * j + 20);
            }
            BAR();
        }
    } else if (wid == 2) {
        // ============ feat stager: 8-w chunks, 4-deep pipeline ============
        const int n = lane >> 1, wl = 4 * (lane & 1);
        const int xr = (n & 7) << 3;
        const int rowt = n * 64;

        auto stage = [&](int buf, int wb) {
            unsigned short* half = fs[buf];
            f32x4 A[8], Bv[8], Cv[8], Dv[8];
            auto LD = [&](f32x4 (&R)[8], int g) {
                #pragma unroll
                for (int k = 0; k < 8; ++k)
                    R[k] = *(const f32x4*)(fb + (size_t)(8 * g + k) * 65536
                                              + n * 256 + wb + wl);
            };
            auto WR = [&](const f32x4 (&R)[8], int g) {
                #pragma unroll
                for (int k = 0; k < 8; ++k) {
                    const int rb = (rowt + (8 * g + k)) ^ xr;
                    #pragma unroll
                    for (int e = 0; e < 4; ++e)
                        half[(wl + e) * 2048 + rb] =
                            __bfloat16_as_ushort(__float2bfloat16(R[k][e]));
                }
            };
            LD(A, 0); LD(Bv, 1); LD(Cv, 2); LD(Dv, 3);
            WR(A, 0); LD(A, 4);
            WR(Bv, 1); LD(Bv, 5);
            WR(Cv, 2); LD(Cv, 6);
            WR(Dv, 3); LD(Dv, 7);
            WR(A, 4); WR(Bv, 5); WR(Cv, 6); WR(Dv, 7);
        };

        stage(kS & 1, 8 * kS);
        BAR();
        #pragma unroll 1
        for (int j = kS; j < kE; ++j) {
            if (((j & 1) == 0) && (j >= j0 + 2)) BAR();
            if (j + 1 < kE) stage((j + 1) & 1, 8 * (j + 1));
            BAR();
        }
    } else {
        // ============ out drainer: 16-w pairs -> full 64B lines ============
        const int r4 = lane >> 2, wq = lane & 3;

        auto drain_pair = [&](int m) {   // m = even chunk idx; w-base = 8*m
            #pragma unroll 8
            for (int i = 0; i < 128; ++i) {
                const int o = i >> 1;
                const int n2 = ((i & 1) << 4) + r4;
                const int idx = (o * 512 + n2 * 16 + 4 * wq) ^ (((o >> 2) & 3) << 2);
                short4v d = *(const short4v*)&og16[idx];
                f32x4 v = { b2f(d.x), b2f(d.y), b2f(d.z), b2f(d.w) };
                *(f32x4*)(outp + ((size_t)(b * 64 + o) * 256 + h0 + n2) * 256
                          + 8 * m + 4 * wq) = v;
            }
        };

        BAR();
        #pragma unroll 1
        for (int j = kS; j < kE; ++j) {
            if (((j & 1) == 0) && (j >= j0 + 2)) { drain_pair(j - 2); BAR(); }
            BAR();
        }
        drain_pair(kE - 2);
    }
}

extern "C" void kernel_launch(void* const* d_in, const int* in_sizes, int n_in,
                              void* d_out, int out_size, void* d_ws, size_t ws_size,
                              hipStream_t stream) {
    const float* feat = (const float*)d_in[0];
    const float* conf = (const float*)d_in[1];
    const float* Wi   = (const float*)d_in[2];
    const float* bi   = (const float*)d_in[3];
    const float* Ws   = (const float*)d_in[4];
    const float* bs   = (const float*)d_in[5];
    const float* bias = (const float*)d_in[6];
    float* out = (float*)d_out;
    (void)d_ws; (void)ws_size; (void)in_sizes; (void)n_in; (void)out_size;

    dp_v12_kernel<<<256, 256, 0, stream>>>(feat, conf, Wi, bi, Ws, bs, bias, out);
}

// Round 13
// 180.238 us; speedup vs baseline: 9.1952x; 1.4365x over previous
//
#include <hip/hip_runtime.h>
#include <hip/hip_bf16.h>

// DirectionalPropagation1D v13 = v9 with ONE change: the feat stager uses a
// T14 issue-early/write-late schedule (loads for chunk j+2 issued in the same
// phase that writes chunk j+1's landed registers to LDS; 4 statically-named
// pi register sets). Each ds_write waits only on loads issued a full phase
// earlier -> load queue stays 24-32 deep per wave (v5/v9's interleaved
// stage() drained it to ~8). Tests the concurrency-vs-granule explanation of
// the 3.0 TB/s law (time = hbm_bytes / 3.0 TB/s across R2-R12).
// Everything else (rec wave, drainer, gates, og, barriers) = v9 verbatim.

typedef __attribute__((ext_vector_type(8))) short short8;
typedef __attribute__((ext_vector_type(4))) short short4v;
typedef __attribute__((ext_vector_type(2))) short short2v;
typedef __attribute__((ext_vector_type(4))) float f32x4;

union FragU { unsigned int u[4]; short8 v; };
union PkU { unsigned int u; short2v s2; };

__device__ __forceinline__ unsigned int pk2(float a, float b) {
    unsigned short lo = __bfloat16_as_ushort(__float2bfloat16(a));
    unsigned short hi = __bfloat16_as_ushort(__float2bfloat16(b));
    return (unsigned int)lo | ((unsigned int)hi << 16);
}
__device__ __forceinline__ float b2f(short x) {
    return __uint_as_float(((unsigned int)(unsigned short)x) << 16);
}

// feat staging [w16][n16][c64] bf16
__device__ __forceinline__ int fsi(int w, int n, int c) {
    return (w * 1024 + n * 64 + c) ^ ((n & 7) << 3);
}
// out staging [o64][n16][w16] bf16 (same pure function both sides)
__device__ __forceinline__ int ogi(int o, int n, int w) {
    return (o * 256 + n * 16 + w) ^ ((((o >> 2) ^ (n >> 2)) & 3) << 2);
}

// LDS-only barrier: global traffic stays in flight across it.
#define BAR() asm volatile("s_waitcnt lgkmcnt(0)\n\ts_barrier" ::: "memory")

__global__ __launch_bounds__(256, 1) void dp_v13_kernel(
    const float* __restrict__ feat, const float* __restrict__ conf,
    const float* __restrict__ Wi, const float* __restrict__ bi,
    const float* __restrict__ Ws, const float* __restrict__ bs,
    const float* __restrict__ bias, float* __restrict__ outp)
{
    __shared__ unsigned short fs[2][16384];  // 64 KB feat bf16, ping-pong
    __shared__ unsigned short og[2][16384];  // 64 KB out bf16, ping-pong
    __shared__ float gs[4][256];             //  4 KB gates [slot][w16*16+n]

    const int tid = threadIdx.x;
    const int lane = tid & 63;
    const int wid = tid >> 6;
    const int l15 = lane & 15, g4 = lane >> 4;
    const int nb = blockIdx.x;
    const int b = nb >> 4, h0 = (nb & 15) * 16;

    const float* fb = feat + (size_t)b * 64 * 65536 + (size_t)h0 * 256;

    if (wid == 0) {
        // ================= recurrence wave (v9 verbatim) =================
        FragU Ai[4][2], As[4][2];
        #pragma unroll
        for (int t = 0; t < 4; ++t)
            #pragma unroll
            for (int h = 0; h < 2; ++h) {
                const float* si = Wi + (16 * t + l15) * 64 + 32 * h + g4 * 8;
                const float* ss = Ws + (16 * t + l15) * 64;
                #pragma unroll
                for (int d = 0; d < 4; ++d) {
                    Ai[t][h].u[d] = pk2(si[2 * d], si[2 * d + 1]);
                    const int c0 = 16 * (2 * h + (d >> 1)) + 4 * g4 + 2 * (d & 1);
                    As[t][h].u[d] = pk2(ss[c0], ss[c0 + 1]);
                }
            }
        f32x4 binit[4];
        #pragma unroll
        for (int t = 0; t < 4; ++t)
            #pragma unroll
            for (int r = 0; r < 4; ++r) {
                int o = 16 * t + 4 * g4 + r;
                binit[t][r] = bi[o] + bs[o] + bias[o];
            }

        FragU S0, S1;
        #pragma unroll
        for (int d = 0; d < 4; ++d) { S0.u[d] = 0u; S1.u[d] = 0u; }

        const int fo0 = (l15 * 64 + 8 * g4) ^ ((l15 & 7) << 3);
        const int fo1 = (l15 * 64 + 32 + 8 * g4) ^ ((l15 & 7) << 3);
        const int swz = ((g4 ^ (l15 >> 2)) & 3) << 2;
        const int ogl = g4 * 1024 + l15 * 16;

        float curE[4][4];

        auto mstep = [&](const short8& F0, const short8& F1, float (&cur)[4][4]) {
            f32x4 a0 = binit[0], a1 = binit[1], a2 = binit[2], a3 = binit[3];
            a0 = __builtin_amdgcn_mfma_f32_16x16x32_bf16(Ai[0][0].v, F0, a0, 0, 0, 0);
            a1 = __builtin_amdgcn_mfma_f32_16x16x32_bf16(Ai[1][0].v, F0, a1, 0, 0, 0);
            a2 = __builtin_amdgcn_mfma_f32_16x16x32_bf16(Ai[2][0].v, F0, a2, 0, 0, 0);
            a3 = __builtin_amdgcn_mfma_f32_16x16x32_bf16(Ai[3][0].v, F0, a3, 0, 0, 0);
            a0 = __builtin_amdgcn_mfma_f32_16x16x32_bf16(Ai[0][1].v, F1, a0, 0, 0, 0);
            a1 = __builtin_amdgcn_mfma_f32_16x16x32_bf16(Ai[1][1].v, F1, a1, 0, 0, 0);
            a2 = __builtin_amdgcn_mfma_f32_16x16x32_bf16(Ai[2][1].v, F1, a2, 0, 0, 0);
            a3 = __builtin_amdgcn_mfma_f32_16x16x32_bf16(Ai[3][1].v, F1, a3, 0, 0, 0);
            a0 = __builtin_amdgcn_mfma_f32_16x16x32_bf16(As[0][0].v, S0.v, a0, 0, 0, 0);
            a1 = __builtin_amdgcn_mfma_f32_16x16x32_bf16(As[1][0].v, S0.v, a1, 0, 0, 0);
            a2 = __builtin_amdgcn_mfma_f32_16x16x32_bf16(As[2][0].v, S0.v, a2, 0, 0, 0);
            a3 = __builtin_amdgcn_mfma_f32_16x16x32_bf16(As[3][0].v, S0.v, a3, 0, 0, 0);
            a0 = __builtin_amdgcn_mfma_f32_16x16x32_bf16(As[0][1].v, S1.v, a0, 0, 0, 0);
            a1 = __builtin_amdgcn_mfma_f32_16x16x32_bf16(As[1][1].v, S1.v, a1, 0, 0, 0);
            a2 = __builtin_amdgcn_mfma_f32_16x16x32_bf16(As[2][1].v, S1.v, a2, 0, 0, 0);
            a3 = __builtin_amdgcn_mfma_f32_16x16x32_bf16(As[3][1].v, S1.v, a3, 0, 0, 0);
            #pragma unroll
            for (int r = 0; r < 4; ++r) {
                cur[0][r] = fmaxf(a0[r], 0.f);
                cur[1][r] = fmaxf(a1[r], 0.f);
                cur[2][r] = fmaxf(a2[r], 0.f);
                cur[3][r] = fmaxf(a3[r], 0.f);
            }
        };
        auto rebuild = [&](const float (&cur)[4][4], float gv) {
            float g0[4], g1[4], g2[4], g3[4];
            #pragma unroll
            for (int r = 0; r < 4; ++r) {
                g0[r] = cur[0][r] * gv; g1[r] = cur[1][r] * gv;
                g2[r] = cur[2][r] * gv; g3[r] = cur[3][r] * gv;
            }
            S0.u[0] = pk2(g0[0], g0[1]); S0.u[1] = pk2(g0[2], g0[3]);
            S0.u[2] = pk2(g1[0], g1[1]); S0.u[3] = pk2(g1[2], g1[3]);
            S1.u[0] = pk2(g2[0], g2[1]); S1.u[1] = pk2(g2[2], g2[3]);
            S1.u[2] = pk2(g3[0], g3[1]); S1.u[3] = pk2(g3[2], g3[3]);
        };

        BAR();  // prologue barrier

        #pragma unroll 1
        for (int cc = 0; cc < 16; ++cc) {
            const unsigned short* fsb = fs[cc & 1];
            unsigned short* ogb = og[cc & 1];
            const float* gsc = gs[cc & 3];
            const float* gsn = gs[(cc + 1) & 3];

            short8 Fn0 = *(const short8*)&fsb[fo0];
            short8 Fn1 = *(const short8*)&fsb[fo1];

            #pragma unroll 1
            for (int up = 0; up < 8; ++up) {
                // ---- even step u = 2*up ----
                {
                    const int u = 2 * up;
                    short8 F0 = Fn0, F1 = Fn1;
                    Fn0 = *(const short8*)&fsb[(u + 1) * 1024 + fo0];
                    Fn1 = *(const short8*)&fsb[(u + 1) * 1024 + fo1];
                    float gvn = gsc[(u + 1) * 16 + l15];
                    float cur[4][4];
                    mstep(F0, F1, cur);
                    #pragma unroll
                    for (int t = 0; t < 4; ++t)
                        #pragma unroll
                        for (int r = 0; r < 4; ++r) curE[t][r] = cur[t][r];
                    rebuild(cur, gvn);
                }
                // ---- odd step u = 2*up+1 ----
                {
                    const int u = 2 * up + 1;
                    short8 F0 = Fn0, F1 = Fn1;
                    if (up < 7) {
                        Fn0 = *(const short8*)&fsb[(u + 1) * 1024 + fo0];
                        Fn1 = *(const short8*)&fsb[(u + 1) * 1024 + fo1];
                    }
                    float gvn = (up < 7) ? gsc[(u + 1) * 16 + l15] : gsn[l15];
                    float cur[4][4];
                    mstep(F0, F1, cur);
                    unsigned short* opb = ogb + ogl + ((u - 1) ^ swz);
                    #pragma unroll
                    for (int t = 0; t < 4; ++t)
                        #pragma unroll
                        for (int r = 0; r < 4; ++r) {
                            PkU pk; pk.u = pk2(curE[t][r], cur[t][r]);
                            *(short2v*)&opb[t * 4096 + r * 256] = pk.s2;
                        }
                    if (!(cc == 15 && up == 7)) rebuild(cur, gvn);
                }
            }
            BAR();
        }
    } else if (wid <= 2) {
        // ========== feat stagers (waves 1,2): T14 issue-early/write-late ==
        const int cb2 = (wid - 1) * 16;
        const int n = lane & 15;

        // four statically-named pi register sets (rule 20)
        f32x4 s0[2][4], s1[2][4], s2[2][4], s3[2][4];

        auto ldp = [&](f32x4 (&R)[2][4], int pi, int w0) {
            const int cp = cb2 + 4 * pi + g4;
            const float* p0 = fb + (size_t)(2 * cp) * 65536 + n * 256 + w0;
            #pragma unroll
            for (int row = 0; row < 2; ++row)
                #pragma unroll
                for (int q = 0; q < 4; ++q)
                    R[row][q] = *(const f32x4*)(p0 + row * 65536 + 4 * q);
        };
        auto wrp = [&](const f32x4 (&R)[2][4], int pi, int buf) {
            const int cp = cb2 + 4 * pi + g4;
            #pragma unroll
            for (int q = 0; q < 4; ++q)
                #pragma unroll
                for (int e = 0; e < 4; ++e) {
                    PkU pk; pk.u = pk2(R[0][q][e], R[1][q][e]);
                    *(short2v*)&fs[buf][fsi(4 * q + e, n, 2 * cp)] = pk.s2;
                }
        };

        // prologue: chunk 0 load+write; chunk 1 loads left in flight
        ldp(s0, 0, 0); ldp(s1, 1, 0); ldp(s2, 2, 0); ldp(s3, 3, 0);
        wrp(s0, 0, 0); wrp(s1, 1, 0); wrp(s2, 2, 0); wrp(s3, 3, 0);
        ldp(s0, 0, 16); ldp(s1, 1, 16); ldp(s2, 2, 16); ldp(s3, 3, 16);
        BAR();
        #pragma unroll 1
        for (int j = 0; j < 16; ++j) {
            if (j < 15) {
                const int buf = (j + 1) & 1;
                const int wn = (j + 2) * 16;
                wrp(s0, 0, buf); if (j < 14) ldp(s0, 0, wn);
                wrp(s1, 1, buf); if (j < 14) ldp(s1, 1, wn);
                wrp(s2, 2, buf); if (j < 14) ldp(s2, 2, wn);
                wrp(s3, 3, buf); if (j < 14) ldp(s3, 3, wn);
            }
            BAR();
        }
    } else {
        // ================= out drainer (wave 3) + gate stager (v9) ========
        const int n = (lane >> 2) & 15, wq = lane & 3;
        float* const ob = outp + ((size_t)(b * 64) * 256 + h0 + n) * 256 + 4 * wq;
        const float* const gbd = conf + ((size_t)(b * 256) + h0 + n) * 256;

        auto drain = [&](int buf, int wpr) {
            #pragma unroll 8
            for (int o = 0; o < 64; ++o) {
                short4v d = *(const short4v*)&og[buf][ogi(o, n, 4 * wq)];
                f32x4 o4 = { b2f(d.x), b2f(d.y), b2f(d.z), b2f(d.w) };
                *(f32x4*)(ob + (size_t)o * 65536 + wpr) = o4;
            }
        };
        auto stage_gs = [&](int k) {
            f32x4 v = *(const f32x4*)(gbd + 16 * k + 4 * wq);
            float* gd = gs[k & 3];
            #pragma unroll
            for (int e = 0; e < 4; ++e) gd[(4 * wq + e) * 16 + n] = v[e];
        };

        stage_gs(0);
        stage_gs(1);
        BAR();
        #pragma unroll 1
        for (int cc = 0; cc < 16; ++cc) {
            if (cc > 0) drain((cc - 1) & 1, (cc - 1) * 16);
            if (cc < 14) stage_gs(cc + 2);
            BAR();
        }
        drain(1, 240);  // final chunk
    }
}

extern "C" void kernel_launch(void* const* d_in, const int* in_sizes, int n_in,
                              void* d_out, int out_size, void* d_ws, size_t ws_size,
                              hipStream_t stream) {
    const float* feat = (const float*)d_in[0];
    const float* conf = (const float*)d_in[1];
    const float* Wi   = (const float*)d_in[2];
    const float* bi   = (const float*)d_in[3];
    const float* Ws   = (const float*)d_in[4];
    const float* bs   = (const float*)d_in[5];
    const float* bias = (const float*)d_in[6];
    float* out = (float*)d_out;
    (void)d_ws; (void)ws_size; (void)in_sizes; (void)n_in; (void)out_size;

    dp_v13_kernel<<<256, 256, 0, stream>>>(feat, conf, Wi, bi, Ws, bs, bias, out);
}